// Round 14
// baseline (145.508 us; speedup 1.0000x reference)
//
#include <hip/hip_runtime.h>

typedef unsigned long long u64;

#define NB 64
#define NQ 900
#define NCLS 81     // C+1
#define NLAB 81     // possible argmax labels 0..80
#define NVERB 117
#define NBQ (NB*NQ)
#define NWORD 15    // max chunks per group (ceil(900/64))

// ---- wave64 max-reduce on the VALU pipe (DPP), result uniform in all lanes.
__device__ __forceinline__ float wave_max_dpp(float m) {
    unsigned mu;
    mu = __float_as_uint(m);
    m = fmaxf(m, __uint_as_float(__builtin_amdgcn_update_dpp(mu, mu, 0x111, 0xF, 0xF, false)));
    mu = __float_as_uint(m);
    m = fmaxf(m, __uint_as_float(__builtin_amdgcn_update_dpp(mu, mu, 0x112, 0xF, 0xF, false)));
    mu = __float_as_uint(m);
    m = fmaxf(m, __uint_as_float(__builtin_amdgcn_update_dpp(mu, mu, 0x114, 0xF, 0xF, false)));
    mu = __float_as_uint(m);
    m = fmaxf(m, __uint_as_float(__builtin_amdgcn_update_dpp(mu, mu, 0x118, 0xF, 0xF, false)));
    mu = __float_as_uint(m);
    m = fmaxf(m, __uint_as_float(__builtin_amdgcn_update_dpp(mu, mu, 0x142, 0xF, 0xF, false)));
    mu = __float_as_uint(m);
    m = fmaxf(m, __uint_as_float(__builtin_amdgcn_update_dpp(mu, mu, 0x143, 0xF, 0xF, false)));
    return __uint_as_float(__builtin_amdgcn_readlane(__float_as_uint(m), 63));
}

// ---- Kernel 0: correct_mat (exactly {0,1}) -> per-class 128-bit verb mask --
__global__ __launch_bounds__(256) void k0(
    const float* __restrict__ cmat, unsigned* __restrict__ bmask)
{
    int idx = blockIdx.x * 256 + threadIdx.x;
    if (idx >= NCLS * 4) return;
    int c = idx >> 2, w = idx & 3;
    unsigned m = 0;
    for (int k = 0; k < 32; ++k) {
        int v = w * 32 + k;
        if (v < NVERB) {
            bool bit = (c < NCLS - 1) ? (cmat[v * (NCLS - 1) + c] > 0.5f) : true;
            if (bit) m |= (1u << k);
        }
    }
    bmask[idx] = m;
}

// ---- Kernel A: 4 rows/wave (best measured), fast div, nontemporal stores --
__global__ __launch_bounds__(256) void kA(
    const float* __restrict__ obj_logits, const float* __restrict__ verb_logits,
    const float* __restrict__ sub_boxes, const float* __restrict__ obj_boxes,
    const int* __restrict__ target_sizes, const uint4* __restrict__ bmask,
    float* __restrict__ out_hoi, float* __restrict__ out_lab,
    float* __restrict__ out_sb, float* __restrict__ out_ob,
    float* __restrict__ ws_max, int* __restrict__ ws_lab,
    float* __restrict__ sar, float* __restrict__ oar)
{
    int wp   = (blockIdx.x * blockDim.x + threadIdx.x) >> 6;
    int lane = threadIdx.x & 63;
    int w0 = wp * 4;                 // 4 rows; 900 % 4 == 0 -> never cross batch
    int b = w0 / NQ;

    // ---- issue ALL 16 global loads first (independent streams) ----
    const float* ol = obj_logits  + (size_t)w0 * NCLS;
    const float* vl = verb_logits + (size_t)w0 * NVERB;
    float A[4], Bv[4], va[4], vb[4];
    #pragma unroll
    for (int r = 0; r < 4; ++r) {
        A[r]  = ol[r * NCLS + lane];
        Bv[r] = (lane < NCLS - 64) ? ol[r * NCLS + 64 + lane] : -3.4e38f;
        va[r] = vl[r * NVERB + lane];
        vb[r] = (lane < NVERB - 64) ? vl[r * NVERB + 64 + lane] : 0.0f;
    }

    // ---- argmax: DPP max + ballot index recovery ----
    float OS[4]; int MI[4];
    #pragma unroll
    for (int r = 0; r < 4; ++r) {
        float m = wave_max_dpp(fmaxf(A[r], Bv[r]));
        u64 balA = __ballot((int)(A[r] == m));
        u64 balB = __ballot((int)(lane < NCLS - 64 && Bv[r] == m));
        MI[r] = balA ? (__ffsll(balA) - 1) : (63 + __ffsll(balB));
        OS[r] = __fdividef(1.0f, 1.0f + __expf(-m));
    }

    // ---- hoi scores: sigmoid * obj_score * bit-mask, row max ----
    float MX[4];
    #pragma unroll
    for (int r = 0; r < 4; ++r) {
        uint4 bm = bmask[MI[r]];
        unsigned wa = (lane < 32) ? bm.x : bm.y;
        unsigned wb = (lane < 32) ? bm.z : bm.w;
        float ka = ((wa >> (lane & 31)) & 1u) ? 1.0f : 0.0f;
        float kb = ((wb >> (lane & 31)) & 1u) ? 1.0f : 0.0f;
        float* oh = out_hoi + (size_t)(w0 + r) * NVERB;
        float ha = __fdividef(OS[r] * ka, 1.0f + __expf(-va[r]));
        float hb = -1.0f;
        if (lane < NVERB - 64) {
            hb = __fdividef(OS[r] * kb, 1.0f + __expf(-vb[r]));
            __builtin_nontemporal_store(hb, &oh[64 + lane]);
        }
        __builtin_nontemporal_store(ha, &oh[lane]);
        MX[r] = wave_max_dpp(fmaxf(ha, hb));
    }

    // ---- scalar per-row outputs (values are wave-uniform) ----
    if (lane < 4) {
        int   mi = (lane == 0) ? MI[0] : (lane == 1) ? MI[1] : (lane == 2) ? MI[2] : MI[3];
        float mx = (lane == 0) ? MX[0] : (lane == 1) ? MX[1] : (lane == 2) ? MX[2] : MX[3];
        out_lab[w0 + lane] = (float)mi;
        ws_lab[w0 + lane]  = mi;
        ws_max[w0 + lane]  = mx;
    }

    // ---- fused box scale + area: lanes 0-7 = {4 rows} x {sub,obj} ----
    if (lane < 8) {
        int row = w0 + (lane >> 1);
        const float* bx = ((lane & 1) == 0 ? sub_boxes : obj_boxes) + (size_t)row * 4;
        float* o = ((lane & 1) == 0 ? out_sb : out_ob) + (size_t)row * 4;
        float ih = (float)target_sizes[b * 2 + 0];
        float iw = (float)target_sizes[b * 2 + 1];
        float4 v = *(const float4*)bx;
        float x1 = (v.x - 0.5f * v.z) * iw, y1 = (v.y - 0.5f * v.w) * ih;
        float x2 = (v.x + 0.5f * v.z) * iw, y2 = (v.y + 0.5f * v.w) * ih;
        *(float4*)o = make_float4(x1, y1, x2, y2);
        float ar = (x2 - x1 + 1.0f) * (y2 - y1 + 1.0f);
        ((lane & 1) == 0 ? sar : oar)[row] = ar;
    }
}

// ---- Kernel B: wave-per-q rank-by-count; emits ws_ord + sorted labels -----
__global__ __launch_bounds__(256) void kB(
    const float* __restrict__ ws_max, const int* __restrict__ ws_lab,
    int* __restrict__ ws_ord, int* __restrict__ slab)
{
    __shared__ float sc[NQ];
    int b = blockIdx.y, t = threadIdx.x;
    for (int i = t; i < NQ; i += 256) sc[i] = ws_max[b * NQ + i];
    __syncthreads();
    int lane = t & 63, wv = t >> 6;
    int q = blockIdx.x * 4 + wv;             // grid.x = 225, 225*4 = 900
    float sq = sc[q];
    int rank = 0;
    #pragma unroll
    for (int c = 0; c < NWORD; ++c) {
        int j = c * 64 + lane;
        float sj = sc[min(j, NQ - 1)];
        bool p = (j < NQ) && ((sj > sq) || (sj == sq && j < q));
        rank += __popcll(__ballot((int)p));
    }
    if (lane == 0) {
        int dst = b * NQ + rank;
        ws_ord[dst] = q;
        slab[dst]   = ws_lab[b * NQ + q];
    }
}

// ---------------- Kernel E: per-(batch,label) greedy NMS, one wave each ----
__device__ __forceinline__ float bc(float x, int r) {
    return __uint_as_float(__builtin_amdgcn_readlane(__float_as_uint(x), r));
}

__device__ __forceinline__ bool iou_pred(
    const float4& sj, const float4& oj, float saj, float oaj,
    float six, float siy, float siz, float siw,
    float oix, float oiy, float oiz, float oiw, float sai, float oai)
{
    float xx1 = fmaxf(six, sj.x), yy1 = fmaxf(siy, sj.y);
    float xx2 = fminf(siz, sj.z), yy2 = fminf(siw, sj.w);
    float w = fmaxf(0.0f, xx2 - xx1 + 1.0f);
    float h = fmaxf(0.0f, yy2 - yy1 + 1.0f);
    float iS = w * h, uS = sai + saj - iS;
    xx1 = fmaxf(oix, oj.x); yy1 = fmaxf(oiy, oj.y);
    xx2 = fminf(oiz, oj.z); yy2 = fminf(oiw, oj.w);
    w = fmaxf(0.0f, xx2 - xx1 + 1.0f);
    h = fmaxf(0.0f, yy2 - yy1 + 1.0f);
    float iO = w * h, uO = oai + oaj - iO;
    // iouS * sqrt(iouO) > 0.7  <=>  iS^2*iO > 0.49*uS^2*uO  (all nonneg)
    return iS * iS * iO > 0.49f * uS * uS * uO;
}

__global__ __launch_bounds__(256) void kE(
    const float* __restrict__ out_sb, const float* __restrict__ out_ob,
    const float* __restrict__ sar, const float* __restrict__ oar,
    const int* __restrict__ slab, const int* __restrict__ ws_ord,
    float* __restrict__ out_keep)
{
    __shared__ unsigned short mem[4][NQ];   // per-wave member ORIGINAL indices
    __shared__ u64 keptm[4][NWORD];         // per-wave kept bits per chunk
    const float4* sb4 = (const float4*)out_sb;
    const float4* ob4 = (const float4*)out_ob;
    int b = blockIdx.y, base = b * NQ;
    int lane = threadIdx.x & 63, wv = threadIdx.x >> 6;
    int l = blockIdx.x * 4 + wv;
    if (l >= NLAB) return;

    // ---- collect members of label l in rank order (ballot-compaction) ----
    int g = 0;
    for (int k0_ = 0; k0_ < NQ; k0_ += 64) {
        int k = k0_ + lane;
        int lb = (k < NQ) ? slab[base + k] : -1;
        int oq = (k < NQ) ? ws_ord[base + k] : 0;
        u64 bal = __ballot((int)(lb == l));
        if (lb == l) {
            int pos = g + __popcll(bal & (((u64)1 << lane) - 1));
            mem[wv][pos] = (unsigned short)oq;
        }
        g += __popcll(bal);
    }

    int nch = (g + 63) >> 6;
    for (int c = 0; c < nch; ++c) {
        int rows = min(64, g - c * 64);
        bool vld = lane < rows;
        int oq = vld ? (int)mem[wv][c * 64 + lane] : 0;
        float4 sj = sb4[base + oq];
        float4 oj = ob4[base + oq];
        float saj = sar[base + oq], oaj = oar[base + oq];

        // ---- cross-chunk: suppression by kept members of earlier chunks ----
        u64 pre = 0ull;
        for (int e = 0; e < c; ++e) {
            int oqE = (int)mem[wv][e * 64 + lane];   // chunk e is always full
            float4 sE = sb4[base + oqE];
            float4 oE = ob4[base + oqE];
            float saE = sar[base + oqE], oaE = oar[base + oqE];
            u64 ke = keptm[wv][e];
            for (int r = 0; r < 64; ++r) {
                if ((ke >> r) & 1ull) {
                    bool p = vld && iou_pred(sj, oj, saj, oaj,
                        bc(sE.x, r), bc(sE.y, r), bc(sE.z, r), bc(sE.w, r),
                        bc(oE.x, r), bc(oE.y, r), bc(oE.z, r), bc(oE.w, r),
                        bc(saE, r), bc(oaE, r));
                    pre |= __ballot((int)p);
                }
            }
        }

        // ---- within-chunk cand words: lane r keeps row r's column word ----
        u64 myword = 0ull;
        for (int r = 0; r < rows; ++r) {
            bool p = vld && (lane > r) && iou_pred(sj, oj, saj, oaj,
                bc(sj.x, r), bc(sj.y, r), bc(sj.z, r), bc(sj.w, r),
                bc(oj.x, r), bc(oj.y, r), bc(oj.z, r), bc(oj.w, r),
                bc(saj, r), bc(oaj, r));
            u64 bal = __ballot((int)p);
            if (lane == r) myword = bal;
        }

        // ---- sequential resolution (SALU chain over uniform values) ----
        unsigned ilo = (unsigned)myword, ihi = (unsigned)(myword >> 32);
        u64 supp = pre;
        for (int r = 0; r < rows; ++r) {
            u64 rowr = ((u64)__builtin_amdgcn_readlane(ihi, r) << 32)
                     |  (u64)__builtin_amdgcn_readlane(ilo, r);
            supp |= ((supp >> r) & 1ull) ? 0ull : rowr;
        }
        u64 keep = ~supp;
        if (lane == 0)
            keptm[wv][c] = keep & ((rows == 64) ? ~0ull : (((u64)1 << rows) - 1));
        if (vld)
            out_keep[base + oq] = ((keep >> lane) & 1ull) ? 1.0f : 0.0f;
    }
}

extern "C" void kernel_launch(void* const* d_in, const int* in_sizes, int n_in,
                              void* d_out, int out_size, void* d_ws, size_t ws_size,
                              hipStream_t stream)
{
    const float* obj_logits   = (const float*)d_in[0];
    const float* verb_logits  = (const float*)d_in[1];
    const float* sub_boxes    = (const float*)d_in[2];
    const float* obj_boxes    = (const float*)d_in[3];
    const int*   target_sizes = (const int*)d_in[4];
    const float* cmat         = (const float*)d_in[5];

    float* out      = (float*)d_out;
    float* out_hoi  = out;
    float* out_lab  = out_hoi + (size_t)NBQ * NVERB;
    float* out_sb   = out_lab + NBQ;
    float* out_ob   = out_sb + (size_t)NBQ * 4;
    float* out_keep = out_ob + (size_t)NBQ * 4;

    // workspace layout
    char* w = (char*)d_ws;
    float*    ws_max = (float*)w;        w += (size_t)NBQ * 4;
    float*    sar    = (float*)w;        w += (size_t)NBQ * 4;
    float*    oar    = (float*)w;        w += (size_t)NBQ * 4;
    int*      ws_lab = (int*)w;          w += (size_t)NBQ * 4;
    int*      slab   = (int*)w;          w += (size_t)NBQ * 4;
    int*      ws_ord = (int*)w;          w += (size_t)NBQ * 4;
    unsigned* bmask  = (unsigned*)w;     w += (size_t)NCLS * 4 * 4;

    k0<<<(NCLS * 4 + 255) / 256, 256, 0, stream>>>(cmat, bmask);
    kA<<<NBQ / 16, 256, 0, stream>>>(obj_logits, verb_logits,
                                     sub_boxes, obj_boxes, target_sizes,
                                     (const uint4*)bmask,
                                     out_hoi, out_lab, out_sb, out_ob,
                                     ws_max, ws_lab, sar, oar);
    // MEASUREMENT ROUND 2: kB and kE each launched 3x (both idempotent).
    // Delta vs R12 = 2*(t_kB + t_kE) + 4*dispatch_overhead.
    for (int rep = 0; rep < 3; ++rep)
        kB<<<dim3(NQ / 4, NB), 256, 0, stream>>>(ws_max, ws_lab, ws_ord, slab);
    for (int rep = 0; rep < 3; ++rep)
        kE<<<dim3((NLAB + 3) / 4, NB), 256, 0, stream>>>(out_sb, out_ob, sar, oar,
                                                         slab, ws_ord, out_keep);
}

// Round 15
// 108.041 us; speedup vs baseline: 1.3468x; 1.3468x over previous
//
#include <hip/hip_runtime.h>

typedef unsigned long long u64;

#define NB 64
#define NQ 900
#define NCLS 81     // C+1
#define NLAB 81
#define NVERB 117
#define NBQ (NB*NQ)
#define NWORD 15    // ceil(900/64)

// ---- wave64 max-reduce on the VALU pipe (DPP), result uniform in all lanes.
__device__ __forceinline__ float wave_max_dpp(float m) {
    unsigned mu;
    mu = __float_as_uint(m);
    m = fmaxf(m, __uint_as_float(__builtin_amdgcn_update_dpp(mu, mu, 0x111, 0xF, 0xF, false)));
    mu = __float_as_uint(m);
    m = fmaxf(m, __uint_as_float(__builtin_amdgcn_update_dpp(mu, mu, 0x112, 0xF, 0xF, false)));
    mu = __float_as_uint(m);
    m = fmaxf(m, __uint_as_float(__builtin_amdgcn_update_dpp(mu, mu, 0x114, 0xF, 0xF, false)));
    mu = __float_as_uint(m);
    m = fmaxf(m, __uint_as_float(__builtin_amdgcn_update_dpp(mu, mu, 0x118, 0xF, 0xF, false)));
    mu = __float_as_uint(m);
    m = fmaxf(m, __uint_as_float(__builtin_amdgcn_update_dpp(mu, mu, 0x142, 0xF, 0xF, false)));
    mu = __float_as_uint(m);
    m = fmaxf(m, __uint_as_float(__builtin_amdgcn_update_dpp(mu, mu, 0x143, 0xF, 0xF, false)));
    return __uint_as_float(__builtin_amdgcn_readlane(__float_as_uint(m), 63));
}

// ===== K1: fused mask-transpose + scores/labels/boxes =====================
// 225 blocks x 1024 threads; each block: LDS cmat transpose, then 256 rows
// (16 waves x 4 iterations x 4-row wave body — body proven through R12).
__global__ __launch_bounds__(1024) void kA(
    const float* __restrict__ obj_logits, const float* __restrict__ verb_logits,
    const float* __restrict__ sub_boxes, const float* __restrict__ obj_boxes,
    const int* __restrict__ target_sizes, const float* __restrict__ cmat,
    float* __restrict__ out_hoi, float* __restrict__ out_lab,
    float* __restrict__ out_sb, float* __restrict__ out_ob,
    float* __restrict__ ws_max, int* __restrict__ ws_lab,
    float* __restrict__ sar, float* __restrict__ oar)
{
    __shared__ float cmT[80 * 117];          // cmT[c*117+v] = cmat[v*80+c]
    int t = threadIdx.x, lane = t & 63, wv = t >> 6;
    for (int i = t; i < 80 * 117; i += 1024) {
        int v = i / 80, c = i - v * 80;
        cmT[c * 117 + v] = cmat[i];
    }
    __syncthreads();

    #pragma unroll
    for (int it = 0; it < 4; ++it) {
        int w0 = blockIdx.x * 256 + wv * 16 + it * 4;   // 4-row group, 4-aligned
        int b = w0 / NQ;

        const float* ol = obj_logits  + (size_t)w0 * NCLS;
        const float* vl = verb_logits + (size_t)w0 * NVERB;
        float A[4], Bv[4], va[4], vb[4];
        #pragma unroll
        for (int r = 0; r < 4; ++r) {
            A[r]  = ol[r * NCLS + lane];
            Bv[r] = (lane < NCLS - 64) ? ol[r * NCLS + 64 + lane] : -3.4e38f;
            va[r] = vl[r * NVERB + lane];
            vb[r] = (lane < NVERB - 64) ? vl[r * NVERB + 64 + lane] : 0.0f;
        }

        float OS[4]; int MI[4];
        #pragma unroll
        for (int r = 0; r < 4; ++r) {
            float m = wave_max_dpp(fmaxf(A[r], Bv[r]));
            u64 balA = __ballot((int)(A[r] == m));
            u64 balB = __ballot((int)(lane < NCLS - 64 && Bv[r] == m));
            MI[r] = balA ? (__ffsll(balA) - 1) : (63 + __ffsll(balB));
            OS[r] = __fdividef(1.0f, 1.0f + __expf(-m));
        }

        float MX[4];
        #pragma unroll
        for (int r = 0; r < 4; ++r) {
            float ka = (MI[r] < 80) ? cmT[MI[r] * 117 + lane] : 1.0f;
            float kb = 0.0f;
            if (lane < NVERB - 64)
                kb = (MI[r] < 80) ? cmT[MI[r] * 117 + 64 + lane] : 1.0f;
            float* oh = out_hoi + (size_t)(w0 + r) * NVERB;
            float ha = __fdividef(OS[r] * ka, 1.0f + __expf(-va[r]));
            float hb = -1.0f;
            if (lane < NVERB - 64) {
                hb = __fdividef(OS[r] * kb, 1.0f + __expf(-vb[r]));
                __builtin_nontemporal_store(hb, &oh[64 + lane]);
            }
            __builtin_nontemporal_store(ha, &oh[lane]);
            MX[r] = wave_max_dpp(fmaxf(ha, hb));
        }

        if (lane < 4) {
            int   mi = (lane == 0) ? MI[0] : (lane == 1) ? MI[1] : (lane == 2) ? MI[2] : MI[3];
            float mx = (lane == 0) ? MX[0] : (lane == 1) ? MX[1] : (lane == 2) ? MX[2] : MX[3];
            out_lab[w0 + lane] = (float)mi;
            ws_lab[w0 + lane]  = mi;
            ws_max[w0 + lane]  = mx;
        }

        if (lane < 8) {
            int row = w0 + (lane >> 1);
            const float* bx = ((lane & 1) == 0 ? sub_boxes : obj_boxes) + (size_t)row * 4;
            float* o = ((lane & 1) == 0 ? out_sb : out_ob) + (size_t)row * 4;
            float ih = (float)target_sizes[b * 2 + 0];
            float iw = (float)target_sizes[b * 2 + 1];
            float4 v = *(const float4*)bx;
            float x1 = (v.x - 0.5f * v.z) * iw, y1 = (v.y - 0.5f * v.w) * ih;
            float x2 = (v.x + 0.5f * v.z) * iw, y2 = (v.y + 0.5f * v.w) * ih;
            *(float4*)o = make_float4(x1, y1, x2, y2);
            float ar = (x2 - x1 + 1.0f) * (y2 - y1 + 1.0f);
            ((lane & 1) == 0 ? sar : oar)[row] = ar;
        }
    }
}

// ===== K2: fused sort + per-label greedy NMS, one block per batch ==========
__device__ __forceinline__ float bc(float x, int r) {
    return __uint_as_float(__builtin_amdgcn_readlane(__float_as_uint(x), r));
}

__device__ __forceinline__ bool iou_pred(
    const float4& sj, const float4& oj, float saj, float oaj,
    float six, float siy, float siz, float siw,
    float oix, float oiy, float oiz, float oiw, float sai, float oai)
{
    float xx1 = fmaxf(six, sj.x), yy1 = fmaxf(siy, sj.y);
    float xx2 = fminf(siz, sj.z), yy2 = fminf(siw, sj.w);
    float w = fmaxf(0.0f, xx2 - xx1 + 1.0f);
    float h = fmaxf(0.0f, yy2 - yy1 + 1.0f);
    float iS = w * h, uS = sai + saj - iS;
    xx1 = fmaxf(oix, oj.x); yy1 = fmaxf(oiy, oj.y);
    xx2 = fminf(oiz, oj.z); yy2 = fminf(oiw, oj.w);
    w = fmaxf(0.0f, xx2 - xx1 + 1.0f);
    h = fmaxf(0.0f, yy2 - yy1 + 1.0f);
    float iO = w * h, uO = oai + oaj - iO;
    // iouS * sqrt(iouO) > 0.7  <=>  iS^2*iO > 0.49*uS^2*uO  (all nonneg)
    return iS * iS * iO > 0.49f * uS * uS * uO;
}

__global__ __launch_bounds__(1024) void kBE(
    const float* __restrict__ ws_max, const int* __restrict__ ws_lab,
    const float* __restrict__ out_sb, const float* __restrict__ out_ob,
    const float* __restrict__ sar, const float* __restrict__ oar,
    float* __restrict__ out_keep)
{
    __shared__ float  smax[NQ];
    __shared__ unsigned short slb[NQ];      // labels by original q
    __shared__ unsigned short sord[NQ];     // rank -> original q
    __shared__ unsigned short ssl[NQ];      // rank -> label
    __shared__ float4 sbx[NQ], obx[NQ];     // boxes by original q
    __shared__ float  sarl[NQ], oarl[NQ];   // areas by original q
    __shared__ unsigned short mem[16][NQ];  // per-wave member original q
    __shared__ u64 keptm[16][NWORD];
    int b = blockIdx.x, base = b * NQ;
    int t = threadIdx.x, lane = t & 63, wv = t >> 6;
    const float4* sb4 = (const float4*)out_sb;
    const float4* ob4 = (const float4*)out_ob;

    for (int k = t; k < NQ; k += 1024) {
        smax[k] = ws_max[base + k];
        slb[k]  = (unsigned short)ws_lab[base + k];
        sbx[k]  = sb4[base + k];
        obx[k]  = ob4[base + k];
        sarl[k] = sar[base + k];
        oarl[k] = oar[base + k];
    }
    __syncthreads();

    // ---- stable descending rank-by-count sort (thread-per-q, LDS) ----
    if (t < NQ) {
        float sq = smax[t];
        int rank = 0;
        #pragma unroll 4
        for (int j = 0; j < NQ; ++j) {
            float sj = smax[j];
            rank += (sj > sq) || (sj == sq && j < t);
        }
        sord[rank] = (unsigned short)t;
        ssl[rank]  = slb[t];
    }
    __syncthreads();

    // ---- per-label greedy NMS: 16 waves, labels round-robin ----
    for (int l = wv; l < NLAB; l += 16) {
        int g = 0;
        #pragma unroll
        for (int k0_ = 0; k0_ < NQ; k0_ += 64) {
            int k = k0_ + lane;
            bool isl = (k < NQ) && ((int)ssl[k] == l);
            u64 bal = __ballot((int)isl);
            if (isl) {
                int pos = g + __popcll(bal & (((u64)1 << lane) - 1));
                mem[wv][pos] = sord[k];
            }
            g += __popcll(bal);
        }

        int nch = (g + 63) >> 6;
        for (int c = 0; c < nch; ++c) {
            int rows = min(64, g - c * 64);
            bool vld = lane < rows;
            int oq = vld ? (int)mem[wv][c * 64 + lane] : 0;
            float4 sj = sbx[oq];
            float4 oj = obx[oq];
            float saj = sarl[oq], oaj = oarl[oq];

            u64 pre = 0ull;
            for (int e = 0; e < c; ++e) {
                int oqE = (int)mem[wv][e * 64 + lane];
                float4 sE = sbx[oqE];
                float4 oE = obx[oqE];
                float saE = sarl[oqE], oaE = oarl[oqE];
                u64 ke = keptm[wv][e];
                for (int r = 0; r < 64; ++r) {
                    if ((ke >> r) & 1ull) {
                        bool p = vld && iou_pred(sj, oj, saj, oaj,
                            bc(sE.x, r), bc(sE.y, r), bc(sE.z, r), bc(sE.w, r),
                            bc(oE.x, r), bc(oE.y, r), bc(oE.z, r), bc(oE.w, r),
                            bc(saE, r), bc(oaE, r));
                        pre |= __ballot((int)p);
                    }
                }
            }

            u64 myword = 0ull;
            for (int r = 0; r < rows; ++r) {
                bool p = vld && (lane > r) && iou_pred(sj, oj, saj, oaj,
                    bc(sj.x, r), bc(sj.y, r), bc(sj.z, r), bc(sj.w, r),
                    bc(oj.x, r), bc(oj.y, r), bc(oj.z, r), bc(oj.w, r),
                    bc(saj, r), bc(oaj, r));
                u64 bal = __ballot((int)p);
                if (lane == r) myword = bal;
            }

            unsigned ilo = (unsigned)myword, ihi = (unsigned)(myword >> 32);
            u64 supp = pre;
            for (int r = 0; r < rows; ++r) {
                u64 rowr = ((u64)__builtin_amdgcn_readlane(ihi, r) << 32)
                         |  (u64)__builtin_amdgcn_readlane(ilo, r);
                supp |= ((supp >> r) & 1ull) ? 0ull : rowr;
            }
            u64 keep = ~supp;
            if (lane == 0)
                keptm[wv][c] = keep & ((rows == 64) ? ~0ull : (((u64)1 << rows) - 1));
            if (vld)
                out_keep[base + oq] = ((keep >> lane) & 1ull) ? 1.0f : 0.0f;
        }
    }
}

extern "C" void kernel_launch(void* const* d_in, const int* in_sizes, int n_in,
                              void* d_out, int out_size, void* d_ws, size_t ws_size,
                              hipStream_t stream)
{
    const float* obj_logits   = (const float*)d_in[0];
    const float* verb_logits  = (const float*)d_in[1];
    const float* sub_boxes    = (const float*)d_in[2];
    const float* obj_boxes    = (const float*)d_in[3];
    const int*   target_sizes = (const int*)d_in[4];
    const float* cmat         = (const float*)d_in[5];

    float* out      = (float*)d_out;
    float* out_hoi  = out;
    float* out_lab  = out_hoi + (size_t)NBQ * NVERB;
    float* out_sb   = out_lab + NBQ;
    float* out_ob   = out_sb + (size_t)NBQ * 4;
    float* out_keep = out_ob + (size_t)NBQ * 4;

    char* w = (char*)d_ws;
    float* ws_max = (float*)w;   w += (size_t)NBQ * 4;
    float* sar    = (float*)w;   w += (size_t)NBQ * 4;
    float* oar    = (float*)w;   w += (size_t)NBQ * 4;
    int*   ws_lab = (int*)w;     w += (size_t)NBQ * 4;

    kA<<<NBQ / 256, 1024, 0, stream>>>(obj_logits, verb_logits,
                                       sub_boxes, obj_boxes, target_sizes, cmat,
                                       out_hoi, out_lab, out_sb, out_ob,
                                       ws_max, ws_lab, sar, oar);
    kBE<<<NB, 1024, 0, stream>>>(ws_max, ws_lab, out_sb, out_ob, sar, oar,
                                 out_keep);
}

// Round 16
// 50.401 us; speedup vs baseline: 2.8870x; 2.1436x over previous
//
#include <hip/hip_runtime.h>

typedef unsigned long long u64;

#define NB 64
#define NQ 900
#define NCLS 81     // C+1
#define NLAB 81
#define NVERB 117
#define NBQ (NB*NQ)
#define NWORD 15    // ceil(900/64)

// ---- wave64 max-reduce on the VALU pipe (DPP), result uniform in all lanes.
__device__ __forceinline__ float wave_max_dpp(float m) {
    unsigned mu;
    mu = __float_as_uint(m);
    m = fmaxf(m, __uint_as_float(__builtin_amdgcn_update_dpp(mu, mu, 0x111, 0xF, 0xF, false)));
    mu = __float_as_uint(m);
    m = fmaxf(m, __uint_as_float(__builtin_amdgcn_update_dpp(mu, mu, 0x112, 0xF, 0xF, false)));
    mu = __float_as_uint(m);
    m = fmaxf(m, __uint_as_float(__builtin_amdgcn_update_dpp(mu, mu, 0x114, 0xF, 0xF, false)));
    mu = __float_as_uint(m);
    m = fmaxf(m, __uint_as_float(__builtin_amdgcn_update_dpp(mu, mu, 0x118, 0xF, 0xF, false)));
    mu = __float_as_uint(m);
    m = fmaxf(m, __uint_as_float(__builtin_amdgcn_update_dpp(mu, mu, 0x142, 0xF, 0xF, false)));
    mu = __float_as_uint(m);
    m = fmaxf(m, __uint_as_float(__builtin_amdgcn_update_dpp(mu, mu, 0x143, 0xF, 0xF, false)));
    return __uint_as_float(__builtin_amdgcn_readlane(__float_as_uint(m), 63));
}

// ===== K1: fused mask-transpose + scores/labels/boxes (R15, unchanged) =====
__global__ __launch_bounds__(1024) void kA(
    const float* __restrict__ obj_logits, const float* __restrict__ verb_logits,
    const float* __restrict__ sub_boxes, const float* __restrict__ obj_boxes,
    const int* __restrict__ target_sizes, const float* __restrict__ cmat,
    float* __restrict__ out_hoi, float* __restrict__ out_lab,
    float* __restrict__ out_sb, float* __restrict__ out_ob,
    float* __restrict__ ws_max, int* __restrict__ ws_lab,
    float* __restrict__ sar, float* __restrict__ oar)
{
    __shared__ float cmT[80 * 117];          // cmT[c*117+v] = cmat[v*80+c]
    int t = threadIdx.x, lane = t & 63, wv = t >> 6;
    for (int i = t; i < 80 * 117; i += 1024) {
        int v = i / 80, c = i - v * 80;
        cmT[c * 117 + v] = cmat[i];
    }
    __syncthreads();

    #pragma unroll
    for (int it = 0; it < 4; ++it) {
        int w0 = blockIdx.x * 256 + wv * 16 + it * 4;
        int b = w0 / NQ;

        const float* ol = obj_logits  + (size_t)w0 * NCLS;
        const float* vl = verb_logits + (size_t)w0 * NVERB;
        float A[4], Bv[4], va[4], vb[4];
        #pragma unroll
        for (int r = 0; r < 4; ++r) {
            A[r]  = ol[r * NCLS + lane];
            Bv[r] = (lane < NCLS - 64) ? ol[r * NCLS + 64 + lane] : -3.4e38f;
            va[r] = vl[r * NVERB + lane];
            vb[r] = (lane < NVERB - 64) ? vl[r * NVERB + 64 + lane] : 0.0f;
        }

        float OS[4]; int MI[4];
        #pragma unroll
        for (int r = 0; r < 4; ++r) {
            float m = wave_max_dpp(fmaxf(A[r], Bv[r]));
            u64 balA = __ballot((int)(A[r] == m));
            u64 balB = __ballot((int)(lane < NCLS - 64 && Bv[r] == m));
            MI[r] = balA ? (__ffsll(balA) - 1) : (63 + __ffsll(balB));
            OS[r] = __fdividef(1.0f, 1.0f + __expf(-m));
        }

        float MX[4];
        #pragma unroll
        for (int r = 0; r < 4; ++r) {
            float ka = (MI[r] < 80) ? cmT[MI[r] * 117 + lane] : 1.0f;
            float kb = 0.0f;
            if (lane < NVERB - 64)
                kb = (MI[r] < 80) ? cmT[MI[r] * 117 + 64 + lane] : 1.0f;
            float* oh = out_hoi + (size_t)(w0 + r) * NVERB;
            float ha = __fdividef(OS[r] * ka, 1.0f + __expf(-va[r]));
            float hb = -1.0f;
            if (lane < NVERB - 64) {
                hb = __fdividef(OS[r] * kb, 1.0f + __expf(-vb[r]));
                __builtin_nontemporal_store(hb, &oh[64 + lane]);
            }
            __builtin_nontemporal_store(ha, &oh[lane]);
            MX[r] = wave_max_dpp(fmaxf(ha, hb));
        }

        if (lane < 4) {
            int   mi = (lane == 0) ? MI[0] : (lane == 1) ? MI[1] : (lane == 2) ? MI[2] : MI[3];
            float mx = (lane == 0) ? MX[0] : (lane == 1) ? MX[1] : (lane == 2) ? MX[2] : MX[3];
            out_lab[w0 + lane] = (float)mi;
            ws_lab[w0 + lane]  = mi;
            ws_max[w0 + lane]  = mx;
        }

        if (lane < 8) {
            int row = w0 + (lane >> 1);
            const float* bx = ((lane & 1) == 0 ? sub_boxes : obj_boxes) + (size_t)row * 4;
            float* o = ((lane & 1) == 0 ? out_sb : out_ob) + (size_t)row * 4;
            float ih = (float)target_sizes[b * 2 + 0];
            float iw = (float)target_sizes[b * 2 + 1];
            float4 v = *(const float4*)bx;
            float x1 = (v.x - 0.5f * v.z) * iw, y1 = (v.y - 0.5f * v.w) * ih;
            float x2 = (v.x + 0.5f * v.z) * iw, y2 = (v.y + 0.5f * v.w) * ih;
            *(float4*)o = make_float4(x1, y1, x2, y2);
            float ar = (x2 - x1 + 1.0f) * (y2 - y1 + 1.0f);
            ((lane & 1) == 0 ? sar : oar)[row] = ar;
        }
    }
}

// ===== K2: per-(batch,label) NMS with IN-WAVE group sort (no global sort) ==
// Suppression graph is label-block-diagonal, so only the relative order
// (score desc, orig q asc) WITHIN each label group matters. Collect members
// in q order (= tie order), rank-sort inside the wave, then chunked greedy.
__device__ __forceinline__ float bc(float x, int r) {
    return __uint_as_float(__builtin_amdgcn_readlane(__float_as_uint(x), r));
}

__device__ __forceinline__ bool iou_pred(
    const float4& sj, const float4& oj, float saj, float oaj,
    float six, float siy, float siz, float siw,
    float oix, float oiy, float oiz, float oiw, float sai, float oai)
{
    float xx1 = fmaxf(six, sj.x), yy1 = fmaxf(siy, sj.y);
    float xx2 = fminf(siz, sj.z), yy2 = fminf(siw, sj.w);
    float w = fmaxf(0.0f, xx2 - xx1 + 1.0f);
    float h = fmaxf(0.0f, yy2 - yy1 + 1.0f);
    float iS = w * h, uS = sai + saj - iS;
    xx1 = fmaxf(oix, oj.x); yy1 = fmaxf(oiy, oj.y);
    xx2 = fminf(oiz, oj.z); yy2 = fminf(oiw, oj.w);
    w = fmaxf(0.0f, xx2 - xx1 + 1.0f);
    h = fmaxf(0.0f, yy2 - yy1 + 1.0f);
    float iO = w * h, uO = oai + oaj - iO;
    // iouS * sqrt(iouO) > 0.7  <=>  iS^2*iO > 0.49*uS^2*uO  (all nonneg)
    return iS * iS * iO > 0.49f * uS * uS * uO;
}

__global__ __launch_bounds__(256) void kE(
    const float* __restrict__ ws_max, const int* __restrict__ ws_lab,
    const float* __restrict__ out_sb, const float* __restrict__ out_ob,
    const float* __restrict__ sar, const float* __restrict__ oar,
    float* __restrict__ out_keep)
{
    __shared__ float           msc[4][NQ];  // member scores (q order)
    __shared__ unsigned short  mq[4][NQ];   // member orig q (q order)
    __shared__ unsigned short  mem[4][NQ];  // sorted member orig q
    __shared__ u64 keptm[4][NWORD];
    const float4* sb4 = (const float4*)out_sb;
    const float4* ob4 = (const float4*)out_ob;
    int b = blockIdx.y, base = b * NQ;
    int lane = threadIdx.x & 63, wv = threadIdx.x >> 6;
    int l = blockIdx.x * 4 + wv;
    if (l >= NLAB) return;

    // ---- collect members of label l in q-ascending order ----
    int g = 0;
    for (int k0_ = 0; k0_ < NQ; k0_ += 64) {
        int k = k0_ + lane;
        int   lb = (k < NQ) ? ws_lab[base + k] : -1;
        float sc = (k < NQ) ? ws_max[base + k] : 0.0f;
        u64 bal = __ballot((int)(lb == l));
        if (lb == l) {
            int pos = g + __popcll(bal & (((u64)1 << lane) - 1));
            msc[wv][pos] = sc;
            mq[wv][pos]  = (unsigned short)k;
        }
        g += __popcll(bal);
    }

    // ---- in-wave stable rank sort by (score desc, q asc) ----
    int nch = (g + 63) >> 6;
    for (int cm = 0; cm < nch; ++cm) {
        int m = cm * 64 + lane;
        bool vld = m < g;
        float s = vld ? msc[wv][m] : 0.0f;
        int   q = vld ? (int)mq[wv][m] : 0;
        int rank = 0;
        for (int j = 0; j < g; ++j) {          // uniform LDS reads (broadcast)
            float sj = msc[wv][j];
            int   qj = mq[wv][j];
            rank += (sj > s) || (sj == s && qj < q);
        }
        if (vld) mem[wv][rank] = (unsigned short)q;
    }

    // ---- chunked greedy NMS over sorted members (proven R9/R12 body) ----
    for (int c = 0; c < nch; ++c) {
        int rows = min(64, g - c * 64);
        bool vld = lane < rows;
        int oq = vld ? (int)mem[wv][c * 64 + lane] : 0;
        float4 sj = sb4[base + oq];
        float4 oj = ob4[base + oq];
        float saj = sar[base + oq], oaj = oar[base + oq];

        u64 pre = 0ull;
        for (int e = 0; e < c; ++e) {
            int oqE = (int)mem[wv][e * 64 + lane];
            float4 sE = sb4[base + oqE];
            float4 oE = ob4[base + oqE];
            float saE = sar[base + oqE], oaE = oar[base + oqE];
            u64 ke = keptm[wv][e];
            for (int r = 0; r < 64; ++r) {
                if ((ke >> r) & 1ull) {
                    bool p = vld && iou_pred(sj, oj, saj, oaj,
                        bc(sE.x, r), bc(sE.y, r), bc(sE.z, r), bc(sE.w, r),
                        bc(oE.x, r), bc(oE.y, r), bc(oE.z, r), bc(oE.w, r),
                        bc(saE, r), bc(oaE, r));
                    pre |= __ballot((int)p);
                }
            }
        }

        u64 myword = 0ull;
        for (int r = 0; r < rows; ++r) {
            bool p = vld && (lane > r) && iou_pred(sj, oj, saj, oaj,
                bc(sj.x, r), bc(sj.y, r), bc(sj.z, r), bc(sj.w, r),
                bc(oj.x, r), bc(oj.y, r), bc(oj.z, r), bc(oj.w, r),
                bc(saj, r), bc(oaj, r));
            u64 bal = __ballot((int)p);
            if (lane == r) myword = bal;
        }

        unsigned ilo = (unsigned)myword, ihi = (unsigned)(myword >> 32);
        u64 supp = pre;
        for (int r = 0; r < rows; ++r) {
            u64 rowr = ((u64)__builtin_amdgcn_readlane(ihi, r) << 32)
                     |  (u64)__builtin_amdgcn_readlane(ilo, r);
            supp |= ((supp >> r) & 1ull) ? 0ull : rowr;
        }
        u64 keep = ~supp;
        if (lane == 0)
            keptm[wv][c] = keep & ((rows == 64) ? ~0ull : (((u64)1 << rows) - 1));
        if (vld)
            out_keep[base + oq] = ((keep >> lane) & 1ull) ? 1.0f : 0.0f;
    }
}

extern "C" void kernel_launch(void* const* d_in, const int* in_sizes, int n_in,
                              void* d_out, int out_size, void* d_ws, size_t ws_size,
                              hipStream_t stream)
{
    const float* obj_logits   = (const float*)d_in[0];
    const float* verb_logits  = (const float*)d_in[1];
    const float* sub_boxes    = (const float*)d_in[2];
    const float* obj_boxes    = (const float*)d_in[3];
    const int*   target_sizes = (const int*)d_in[4];
    const float* cmat         = (const float*)d_in[5];

    float* out      = (float*)d_out;
    float* out_hoi  = out;
    float* out_lab  = out_hoi + (size_t)NBQ * NVERB;
    float* out_sb   = out_lab + NBQ;
    float* out_ob   = out_sb + (size_t)NBQ * 4;
    float* out_keep = out_ob + (size_t)NBQ * 4;

    char* w = (char*)d_ws;
    float* ws_max = (float*)w;   w += (size_t)NBQ * 4;
    float* sar    = (float*)w;   w += (size_t)NBQ * 4;
    float* oar    = (float*)w;   w += (size_t)NBQ * 4;
    int*   ws_lab = (int*)w;     w += (size_t)NBQ * 4;

    kA<<<NBQ / 256, 1024, 0, stream>>>(obj_logits, verb_logits,
                                       sub_boxes, obj_boxes, target_sizes, cmat,
                                       out_hoi, out_lab, out_sb, out_ob,
                                       ws_max, ws_lab, sar, oar);
    kE<<<dim3((NLAB + 3) / 4, NB), 256, 0, stream>>>(ws_max, ws_lab,
                                                     out_sb, out_ob, sar, oar,
                                                     out_keep);
}